// Round 1
// baseline (3308.199 us; speedup 1.0000x reference)
//
#include <hip/hip_runtime.h>

// ============================================================
// ScaleEncoder: pool2 -> [LN -> SSM-scan -> resid]x4 (fwd & bwd) -> merge -> upsample
// B=16 T=4096 D=256 N=16 L=4 SCALE=2, Ts=2048
// xw (fp32 residual stream, [2][16][2048][256]) lives in d_out (exactly 67.1MB).
// ws: xn_bf | delta_bf(/merged f32 overlay) | y_bf | dwT | owT | mergeT
// ============================================================

typedef __attribute__((ext_vector_type(8))) short short8;
typedef __attribute__((ext_vector_type(4))) float f32x4;

#define TS 2048
#define DDIM 256

__device__ __forceinline__ unsigned short f2bf(float f) {
  unsigned u = __float_as_uint(f);
  u = u + 0x7FFFu + ((u >> 16) & 1u);
  return (unsigned short)(u >> 16);
}
__device__ __forceinline__ float bf2f(unsigned short h) {
  return __uint_as_float(((unsigned)h) << 16);
}
__device__ __forceinline__ float softplus_full(float x) {
  return fmaxf(x, 0.f) + log1pf(expf(-fabsf(x)));
}

// ---------------- downsample: x[16][4096][256] -> xw[2][16][2048][256]
// dir0: avgpool2; dir1: time-flipped avgpool2
__global__ __launch_bounds__(256) void ds_kernel(const float4* __restrict__ x4,
                                                 float4* __restrict__ xw4) {
  unsigned idx = blockIdx.x * 256u + threadIdx.x;   // < 4,194,304
  unsigned d4 = idx & 63u;
  unsigned j = (idx >> 6) & 2047u;
  unsigned b = (idx >> 17) & 15u;
  unsigned dir = idx >> 21;
  unsigned jj = dir ? (2047u - j) : j;
  unsigned srow = (b << 12) + (jj << 1);            // b*4096 + 2*jj
  float4 v0 = x4[srow * 64u + d4];
  float4 v1 = x4[(srow + 1u) * 64u + d4];
  float4 o;
  o.x = 0.5f * (v0.x + v1.x); o.y = 0.5f * (v0.y + v1.y);
  o.z = 0.5f * (v0.z + v1.z); o.w = 0.5f * (v0.w + v1.w);
  xw4[(((dir << 4) + b) * 2048u + j) * 64u + d4] = o;
}

// ---------------- weight transpose+bf16: dwT/owT [2][4][256][256] (n,k), mergeT [256][512]
__global__ __launch_bounds__(256) void wconv_kernel(
    const float* __restrict__ fdw, const float* __restrict__ bdw,
    const float* __restrict__ fow, const float* __restrict__ bow,
    const float* __restrict__ mw,
    unsigned short* __restrict__ dwT, unsigned short* __restrict__ owT,
    unsigned short* __restrict__ mT) {
  unsigned idx = blockIdx.x * 256u + threadIdx.x;   // < 1,179,648
  if (idx < 524288u) {
    unsigned dir = idx >> 18, l = (idx >> 16) & 3u, n = (idx >> 8) & 255u, k = idx & 255u;
    const float* s = dir ? bdw : fdw;
    dwT[idx] = f2bf(s[((l << 8) + k) * 256u + n]);
  } else if (idx < 1048576u) {
    unsigned r = idx - 524288u;
    unsigned dir = r >> 18, l = (r >> 16) & 3u, n = (r >> 8) & 255u, k = r & 255u;
    const float* s = dir ? bow : fow;
    owT[r] = f2bf(s[((l << 8) + k) * 256u + n]);
  } else {
    unsigned r = idx - 1048576u;                    // < 131072
    unsigned n = r >> 9, k = r & 511u;
    mT[r] = f2bf(mw[(k << 8) + n]);
  }
}

// ---------------- LayerNorm: xw fp32 -> xn bf16 (one wave per 256-row)
__global__ __launch_bounds__(256) void ln_kernel(
    const float* __restrict__ xw, unsigned short* __restrict__ xn,
    const float* __restrict__ fnw, const float* __restrict__ fnb,
    const float* __restrict__ bnw, const float* __restrict__ bnb, int l) {
  unsigned row = (blockIdx.x << 2) + (threadIdx.x >> 6);  // < 65536
  unsigned lane = threadIdx.x & 63u;
  unsigned dir = row >> 15;
  const float* g = (dir ? bnw : fnw) + (l << 8);
  const float* bb = (dir ? bnb : fnb) + (l << 8);
  float4 v = ((const float4*)xw)[(row << 6) + lane];
  float s = v.x + v.y + v.z + v.w;
  float q = v.x * v.x + v.y * v.y + v.z * v.z + v.w * v.w;
  for (int o = 32; o > 0; o >>= 1) { s += __shfl_xor(s, o); q += __shfl_xor(q, o); }
  float m = s * (1.f / 256.f);
  float var = q * (1.f / 256.f) - m * m;
  float r = rsqrtf(var + 1e-5f);
  unsigned dd = lane << 2;
  ushort4 o4 = make_ushort4(
      f2bf((v.x - m) * r * g[dd + 0] + bb[dd + 0]),
      f2bf((v.y - m) * r * g[dd + 1] + bb[dd + 1]),
      f2bf((v.z - m) * r * g[dd + 2] + bb[dd + 2]),
      f2bf((v.w - m) * r * g[dd + 3] + bb[dd + 3]));
  ((ushort4*)xn)[(row << 6) + lane] = o4;
}

// ---------------- layer GEMM: C[65536][256] = A @ W_dir + bias_dir
// MODE 0: delta = softplus(C) -> bf16.  MODE 1: xw += C (residual, fp32).
template <int MODE>
__global__ __launch_bounds__(256) void gemm_layer_k(
    const unsigned short* __restrict__ Abf, const unsigned short* __restrict__ WT,
    const float* __restrict__ bias_f, const float* __restrict__ bias_b, int l,
    unsigned short* __restrict__ delta_out, float* __restrict__ xw) {
  __shared__ __align__(16) unsigned short As[128 * 32];
  __shared__ __align__(16) unsigned short Bs[128 * 32];
  const int tid = threadIdx.x;
  const int lane = tid & 63, wave = tid >> 6;
  const int wm = wave >> 1, wn = wave & 1;
  const int lrow = lane & 15, lhi = lane >> 4;
  const int r0 = blockIdx.y << 7;
  const int c0 = blockIdx.x << 7;
  const int dir = r0 >> 15;                          // 32768 rows per direction
  const unsigned short* W = WT + (((dir << 2) + l) << 16);
  const float* bias = (dir ? bias_b : bias_f) + (l << 8);

  f32x4 acc[4][4] = {};

  for (int k0 = 0; k0 < 256; k0 += 32) {
    __syncthreads();
#pragma unroll
    for (int r = 0; r < 2; ++r) {
      int chunk = (r << 8) + tid;
      int row = chunk >> 2, qq = chunk & 3;
      *(int4*)&As[chunk << 3] =
          *(const int4*)&Abf[(unsigned)(r0 + row) * 256u + (unsigned)(k0 + (qq << 3))];
      *(int4*)&Bs[chunk << 3] =
          *(const int4*)&W[(unsigned)(c0 + row) * 256u + (unsigned)(k0 + (qq << 3))];
    }
    __syncthreads();
    short8 af[4], bfr[4];
#pragma unroll
    for (int m = 0; m < 4; ++m)
      af[m] = *(const short8*)&As[((wm << 6) + (m << 4) + lrow) * 32 + (lhi << 3)];
#pragma unroll
    for (int n = 0; n < 4; ++n)
      bfr[n] = *(const short8*)&Bs[((wn << 6) + (n << 4) + lrow) * 32 + (lhi << 3)];
#pragma unroll
    for (int m = 0; m < 4; ++m)
#pragma unroll
      for (int n = 0; n < 4; ++n)
        acc[m][n] = __builtin_amdgcn_mfma_f32_16x16x32_bf16(af[m], bfr[n], acc[m][n], 0, 0, 0);
  }

#pragma unroll
  for (int m = 0; m < 4; ++m) {
#pragma unroll
    for (int n = 0; n < 4; ++n) {
      const int col = c0 + (wn << 6) + (n << 4) + lrow;
      const float bv = bias[col];
#pragma unroll
      for (int j = 0; j < 4; ++j) {
        const unsigned grow = (unsigned)(r0 + (wm << 6) + (m << 4) + (lhi << 2) + j);
        float v = acc[m][n][j] + bv;
        if (MODE == 0) {
          float sp = fmaxf(v, 0.f) + log1pf(__expf(-fabsf(v)));
          delta_out[grow * 256u + (unsigned)col] = f2bf(sp);
        } else {
          xw[grow * 256u + (unsigned)col] += v;
        }
      }
    }
  }
}

// ---------------- SSM scan: 131072 threads; lane group of 16 = the N dim.
#define ROR_ADD(x, CTRL)                                                          \
  {                                                                               \
    int _r = __builtin_amdgcn_update_dpp(0, __float_as_int(x), CTRL, 0xf, 0xf, 1); \
    x += __int_as_float(_r);                                                      \
  }

__global__ __launch_bounds__(256) void scan_k(
    const unsigned short* __restrict__ delta, const unsigned short* __restrict__ xn,
    unsigned short* __restrict__ y,
    const float* __restrict__ alog_f, const float* __restrict__ alog_b,
    const float* __restrict__ bp_f, const float* __restrict__ bp_b, int l) {
  const unsigned tid = blockIdx.x * 256u + threadIdx.x;
  const int n = tid & 15;
  const int d = (tid >> 4) & 255;
  const int b = (tid >> 12) & 15;
  const int dir = tid >> 16;
  const float* alog = dir ? alog_b : alog_f;
  const float* bp = dir ? bp_b : bp_f;
  const int widx = (l << 12) + (d << 4) + n;
  const float a = softplus_full(alog[widx]) + 1e-4f;
  const float bpv = bp[widx];
  const float aneg = -a;
  unsigned off = (((unsigned)((dir << 4) + b)) << 19) + (unsigned)d;  // (..)*Ts*D + d
  const bool writer = ((threadIdx.x & 15) == 0);
  float s = 0.f;
#pragma unroll 4
  for (int t = 0; t < TS; ++t) {
    float dt = bf2f(delta[off]);
    float xt = bf2f(xn[off]);
    float e = __expf(aneg * dt);
    s = fmaf(e, s, dt * xt * bpv);
    float ys = s;
    ROR_ADD(ys, 0x128);  // row_ror:8
    ROR_ADD(ys, 0x124);  // row_ror:4
    ROR_ADD(ys, 0x122);  // row_ror:2
    ROR_ADD(ys, 0x121);  // row_ror:1
    if (writer) y[off] = f2bf(ys);
    off += 256u;
  }
}

// ---------------- fp32 -> bf16 convert (final x for merge GEMM)
__global__ __launch_bounds__(256) void tobf_kernel(const float4* __restrict__ src,
                                                   ushort4* __restrict__ dst) {
  unsigned idx = blockIdx.x * 256u + threadIdx.x;   // < 4,194,304
  float4 v = src[idx];
  dst[idx] = make_ushort4(f2bf(v.x), f2bf(v.y), f2bf(v.z), f2bf(v.w));
}

// ---------------- merge GEMM: [32768][512] (gathered fwd|flipped-bwd) @ mergeT -> merged fp32
__global__ __launch_bounds__(256) void gemm_merge_k(
    const unsigned short* __restrict__ Xbf, const unsigned short* __restrict__ MT,
    const float* __restrict__ mb, float* __restrict__ merged) {
  __shared__ __align__(16) unsigned short As[128 * 32];
  __shared__ __align__(16) unsigned short Bs[128 * 32];
  const int tid = threadIdx.x;
  const int lane = tid & 63, wave = tid >> 6;
  const int wm = wave >> 1, wn = wave & 1;
  const int lrow = lane & 15, lhi = lane >> 4;
  const int r0 = blockIdx.y << 7;                    // row in [0,32768) = (b,t)
  const int c0 = blockIdx.x << 7;

  f32x4 acc[4][4] = {};

  for (int k0 = 0; k0 < 512; k0 += 32) {
    __syncthreads();
#pragma unroll
    for (int r = 0; r < 2; ++r) {
      int chunk = (r << 8) + tid;
      int row = chunk >> 2, qq = chunk & 3;
      int gr = r0 + row;
      int b = gr >> 11, t = gr & 2047;
      unsigned srow, kk;
      if (k0 < 256) { srow = (unsigned)(b * 2048 + t); kk = (unsigned)k0; }
      else { srow = (unsigned)((16 + b) * 2048 + (2047 - t)); kk = (unsigned)(k0 - 256); }
      *(int4*)&As[chunk << 3] = *(const int4*)&Xbf[(srow << 8) + kk + (unsigned)(qq << 3)];
      *(int4*)&Bs[chunk << 3] =
          *(const int4*)&MT[(unsigned)(c0 + row) * 512u + (unsigned)(k0 + (qq << 3))];
    }
    __syncthreads();
    short8 af[4], bfr[4];
#pragma unroll
    for (int m = 0; m < 4; ++m)
      af[m] = *(const short8*)&As[((wm << 6) + (m << 4) + lrow) * 32 + (lhi << 3)];
#pragma unroll
    for (int n = 0; n < 4; ++n)
      bfr[n] = *(const short8*)&Bs[((wn << 6) + (n << 4) + lrow) * 32 + (lhi << 3)];
#pragma unroll
    for (int m = 0; m < 4; ++m)
#pragma unroll
      for (int n = 0; n < 4; ++n)
        acc[m][n] = __builtin_amdgcn_mfma_f32_16x16x32_bf16(af[m], bfr[n], acc[m][n], 0, 0, 0);
  }

#pragma unroll
  for (int m = 0; m < 4; ++m) {
#pragma unroll
    for (int n = 0; n < 4; ++n) {
      const int col = c0 + (wn << 6) + (n << 4) + lrow;
      const float bv = mb[col];
#pragma unroll
      for (int j = 0; j < 4; ++j) {
        const unsigned grow = (unsigned)(r0 + (wm << 6) + (m << 4) + (lhi << 2) + j);
        merged[grow * 256u + (unsigned)col] = acc[m][n][j] + bv;
      }
    }
  }
}

// ---------------- linear upsample x2 (align_corners=False)
__global__ __launch_bounds__(256) void up_kernel(const float4* __restrict__ m4,
                                                 float4* __restrict__ out4) {
  unsigned idx = blockIdx.x * 256u + threadIdx.x;   // < 4,194,304
  unsigned d4 = idx & 63u;
  unsigned t = (idx >> 6) & 4095u;
  unsigned b = idx >> 18;
  unsigned j = t >> 1;
  unsigned lo, hi; float wlo, whi;
  if (t & 1u) { lo = j; hi = (j < 2047u) ? j + 1u : 2047u; wlo = 0.75f; whi = 0.25f; }
  else { lo = j ? j - 1u : 0u; hi = j; wlo = 0.25f; whi = 0.75f; }
  float4 a = m4[((b << 11) + lo) * 64u + d4];
  float4 c = m4[((b << 11) + hi) * 64u + d4];
  float4 o;
  o.x = wlo * a.x + whi * c.x; o.y = wlo * a.y + whi * c.y;
  o.z = wlo * a.z + whi * c.z; o.w = wlo * a.w + whi * c.w;
  out4[((b << 12) + t) * 64u + d4] = o;
}

// ============================================================
extern "C" void kernel_launch(void* const* d_in, const int* in_sizes, int n_in,
                              void* d_out, int out_size, void* d_ws, size_t ws_size,
                              hipStream_t stream) {
  const float* x    = (const float*)d_in[0];
  const float* fnw  = (const float*)d_in[1];
  const float* fnb  = (const float*)d_in[2];
  const float* fdw  = (const float*)d_in[3];
  const float* fdb  = (const float*)d_in[4];
  const float* falog = (const float*)d_in[5];
  const float* fbp  = (const float*)d_in[6];
  const float* fow  = (const float*)d_in[7];
  const float* fob  = (const float*)d_in[8];
  const float* bnw  = (const float*)d_in[9];
  const float* bnb  = (const float*)d_in[10];
  const float* bdw  = (const float*)d_in[11];
  const float* bdb  = (const float*)d_in[12];
  const float* balog = (const float*)d_in[13];
  const float* bbp  = (const float*)d_in[14];
  const float* bow  = (const float*)d_in[15];
  const float* bob  = (const float*)d_in[16];
  const float* mw   = (const float*)d_in[17];
  const float* mb   = (const float*)d_in[18];

  char* ws = (char*)d_ws;
  const size_t SZ = 33554432;            // 16.78M bf16
  unsigned short* xn_bf    = (unsigned short*)(ws);
  unsigned short* delta_bf = (unsigned short*)(ws + SZ);
  unsigned short* y_bf     = (unsigned short*)(ws + 2 * SZ);
  unsigned short* dwT      = (unsigned short*)(ws + 3 * SZ);
  unsigned short* owT      = dwT + 524288;
  unsigned short* mergeT   = owT + 524288;
  float* merged            = (float*)(ws + SZ);    // overlay delta_bf (dead by merge time)
  float* xw                = (float*)d_out;        // [2][16][2048][256] fp32 residual stream

  wconv_kernel<<<4608, 256, 0, stream>>>(fdw, bdw, fow, bow, mw, dwT, owT, mergeT);
  ds_kernel<<<16384, 256, 0, stream>>>((const float4*)x, (float4*)xw);

  for (int l = 0; l < 4; ++l) {
    ln_kernel<<<16384, 256, 0, stream>>>(xw, xn_bf, fnw, fnb, bnw, bnb, l);
    gemm_layer_k<0><<<dim3(2, 512), 256, 0, stream>>>(xn_bf, dwT, fdb, bdb, l, delta_bf, nullptr);
    scan_k<<<512, 256, 0, stream>>>(delta_bf, xn_bf, y_bf, falog, balog, fbp, bbp, l);
    gemm_layer_k<1><<<dim3(2, 512), 256, 0, stream>>>(y_bf, owT, fob, bob, l, nullptr, xw);
  }

  tobf_kernel<<<16384, 256, 0, stream>>>((const float4*)xw, (ushort4*)xn_bf);
  gemm_merge_k<<<dim3(2, 256), 256, 0, stream>>>(xn_bf, mergeT, mb, merged);
  up_kernel<<<16384, 256, 0, stream>>>((const float4*)merged, (float4*)d_out);
}

// Round 2
// 1456.640 us; speedup vs baseline: 2.2711x; 2.2711x over previous
//
#include <hip/hip_runtime.h>

// ============================================================
// ScaleEncoder: pool2 -> [LN -> SSM-scan -> resid]x4 (fwd & bwd) -> merge -> upsample
// B=16 T=4096 D=256 N=16 L=4 SCALE=2, Ts=2048
// xw (fp32 residual stream, [2][16][2048][256]) lives in d_out (exactly 67.1MB).
// ws: xn_bf | deltaT(/merged f32 overlay) | y_bf | dwT | owT | mergeT | SP
// Scan: chunked 2-pass linear-recurrence (NC chunks), deltaT in [d][t] layout
// for short8 loads; xn stays [t][d].
// ============================================================

typedef __attribute__((ext_vector_type(8))) short short8;
typedef __attribute__((ext_vector_type(4))) float f32x4;

#define TS 2048
#define NSEQ 131072u   // 2*16*256*16 independent recurrences

__device__ __forceinline__ unsigned short f2bf(float f) {
  unsigned u = __float_as_uint(f);
  u = u + 0x7FFFu + ((u >> 16) & 1u);
  return (unsigned short)(u >> 16);
}
__device__ __forceinline__ float bf2f(unsigned short h) {
  return __uint_as_float(((unsigned)h) << 16);
}
__device__ __forceinline__ float softplus_full(float x) {
  return fmaxf(x, 0.f) + log1pf(expf(-fabsf(x)));
}

// ---------------- downsample: x[16][4096][256] -> xw[2][16][2048][256]
__global__ __launch_bounds__(256) void ds_kernel(const float4* __restrict__ x4,
                                                 float4* __restrict__ xw4) {
  unsigned idx = blockIdx.x * 256u + threadIdx.x;   // < 4,194,304
  unsigned d4 = idx & 63u;
  unsigned j = (idx >> 6) & 2047u;
  unsigned b = (idx >> 17) & 15u;
  unsigned dir = idx >> 21;
  unsigned jj = dir ? (2047u - j) : j;
  unsigned srow = (b << 12) + (jj << 1);
  float4 v0 = x4[srow * 64u + d4];
  float4 v1 = x4[(srow + 1u) * 64u + d4];
  float4 o;
  o.x = 0.5f * (v0.x + v1.x); o.y = 0.5f * (v0.y + v1.y);
  o.z = 0.5f * (v0.z + v1.z); o.w = 0.5f * (v0.w + v1.w);
  xw4[(((dir << 4) + b) * 2048u + j) * 64u + d4] = o;
}

// ---------------- weight transpose+bf16
__global__ __launch_bounds__(256) void wconv_kernel(
    const float* __restrict__ fdw, const float* __restrict__ bdw,
    const float* __restrict__ fow, const float* __restrict__ bow,
    const float* __restrict__ mw,
    unsigned short* __restrict__ dwT, unsigned short* __restrict__ owT,
    unsigned short* __restrict__ mT) {
  unsigned idx = blockIdx.x * 256u + threadIdx.x;   // < 1,179,648
  if (idx < 524288u) {
    unsigned dir = idx >> 18, l = (idx >> 16) & 3u, n = (idx >> 8) & 255u, k = idx & 255u;
    const float* s = dir ? bdw : fdw;
    dwT[idx] = f2bf(s[((l << 8) + k) * 256u + n]);
  } else if (idx < 1048576u) {
    unsigned r = idx - 524288u;
    unsigned dir = r >> 18, l = (r >> 16) & 3u, n = (r >> 8) & 255u, k = r & 255u;
    const float* s = dir ? bow : fow;
    owT[r] = f2bf(s[((l << 8) + k) * 256u + n]);
  } else {
    unsigned r = idx - 1048576u;                    // < 131072
    unsigned n = r >> 9, k = r & 511u;
    mT[r] = f2bf(mw[(k << 8) + n]);
  }
}

// ---------------- LayerNorm: xw fp32 -> xn bf16 (one wave per 256-row)
__global__ __launch_bounds__(256) void ln_kernel(
    const float* __restrict__ xw, unsigned short* __restrict__ xn,
    const float* __restrict__ fnw, const float* __restrict__ fnb,
    const float* __restrict__ bnw, const float* __restrict__ bnb, int l) {
  unsigned row = (blockIdx.x << 2) + (threadIdx.x >> 6);  // < 65536
  unsigned lane = threadIdx.x & 63u;
  unsigned dir = row >> 15;
  const float* g = (dir ? bnw : fnw) + (l << 8);
  const float* bb = (dir ? bnb : fnb) + (l << 8);
  float4 v = ((const float4*)xw)[(row << 6) + lane];
  float s = v.x + v.y + v.z + v.w;
  float q = v.x * v.x + v.y * v.y + v.z * v.z + v.w * v.w;
  for (int o = 32; o > 0; o >>= 1) { s += __shfl_xor(s, o); q += __shfl_xor(q, o); }
  float m = s * (1.f / 256.f);
  float var = q * (1.f / 256.f) - m * m;
  float r = rsqrtf(var + 1e-5f);
  unsigned dd = lane << 2;
  ushort4 o4 = make_ushort4(
      f2bf((v.x - m) * r * g[dd + 0] + bb[dd + 0]),
      f2bf((v.y - m) * r * g[dd + 1] + bb[dd + 1]),
      f2bf((v.z - m) * r * g[dd + 2] + bb[dd + 2]),
      f2bf((v.w - m) * r * g[dd + 3] + bb[dd + 3]));
  ((ushort4*)xn)[(row << 6) + lane] = o4;
}

// ---------------- layer GEMM: C[65536][256] = A @ W_dir + bias_dir
// MODE 0: deltaT[dir,b,d,t] = softplus(C) bf16 (transposed, ushort4-packed along t).
// MODE 1: xw += C (residual, fp32).
template <int MODE>
__global__ __launch_bounds__(256) void gemm_layer_k(
    const unsigned short* __restrict__ Abf, const unsigned short* __restrict__ WT,
    const float* __restrict__ bias_f, const float* __restrict__ bias_b, int l,
    unsigned short* __restrict__ delta_out, float* __restrict__ xw) {
  __shared__ __align__(16) unsigned short As[128 * 32];
  __shared__ __align__(16) unsigned short Bs[128 * 32];
  const int tid = threadIdx.x;
  const int lane = tid & 63, wave = tid >> 6;
  const int wm = wave >> 1, wn = wave & 1;
  const int lrow = lane & 15, lhi = lane >> 4;
  const int r0 = blockIdx.y << 7;
  const int c0 = blockIdx.x << 7;
  const int dir = r0 >> 15;
  const unsigned short* W = WT + (((dir << 2) + l) << 16);
  const float* bias = (dir ? bias_b : bias_f) + (l << 8);

  f32x4 acc[4][4] = {};

  for (int k0 = 0; k0 < 256; k0 += 32) {
    __syncthreads();
#pragma unroll
    for (int r = 0; r < 2; ++r) {
      int chunk = (r << 8) + tid;
      int row = chunk >> 2, qq = chunk & 3;
      *(int4*)&As[chunk << 3] =
          *(const int4*)&Abf[(unsigned)(r0 + row) * 256u + (unsigned)(k0 + (qq << 3))];
      *(int4*)&Bs[chunk << 3] =
          *(const int4*)&W[(unsigned)(c0 + row) * 256u + (unsigned)(k0 + (qq << 3))];
    }
    __syncthreads();
    short8 af[4], bfr[4];
#pragma unroll
    for (int m = 0; m < 4; ++m)
      af[m] = *(const short8*)&As[((wm << 6) + (m << 4) + lrow) * 32 + (lhi << 3)];
#pragma unroll
    for (int n = 0; n < 4; ++n)
      bfr[n] = *(const short8*)&Bs[((wn << 6) + (n << 4) + lrow) * 32 + (lhi << 3)];
#pragma unroll
    for (int m = 0; m < 4; ++m)
#pragma unroll
      for (int n = 0; n < 4; ++n)
        acc[m][n] = __builtin_amdgcn_mfma_f32_16x16x32_bf16(af[m], bfr[n], acc[m][n], 0, 0, 0);
  }

  const int seqrow = r0 >> 11;           // dir*16 + b  (constant per block)
  const int tloc = r0 & 2047;            // t base of this block
#pragma unroll
  for (int m = 0; m < 4; ++m) {
#pragma unroll
    for (int n = 0; n < 4; ++n) {
      const int col = c0 + (wn << 6) + (n << 4) + lrow;
      const float bv = bias[col];
      if (MODE == 0) {
        ushort4 pk;
#pragma unroll
        for (int j = 0; j < 4; ++j) {
          float v = acc[m][n][j] + bv;
          float sp = fmaxf(v, 0.f) + log1pf(__expf(-fabsf(v)));
          ((unsigned short*)&pk)[j] = f2bf(sp);
        }
        const unsigned tb = (unsigned)(tloc + (wm << 6) + (m << 4) + (lhi << 2));
        *(ushort4*)&delta_out[(((unsigned)((seqrow << 8) + col)) << 11) + tb] = pk;
      } else {
#pragma unroll
        for (int j = 0; j < 4; ++j) {
          const unsigned grow = (unsigned)(r0 + (wm << 6) + (m << 4) + (lhi << 2) + j);
          xw[grow * 256u + (unsigned)col] += acc[m][n][j] + bv;
        }
      }
    }
  }
}

// ---------------- chunked SSM scan ----------------
// seq id: n (bit0-3) | d (4-11) | b (12-15) | dir (16). 16-lane group = N dim.
#define ROR_ADD(x, CTRL)                                                          \
  {                                                                               \
    int _r = __builtin_amdgcn_update_dpp(0, __float_as_int(x), CTRL, 0xf, 0xf, 1); \
    x += __int_as_float(_r);                                                      \
  }

// pass1: local scan of chunk c (c in [0, NC-1)), store (S, P=exp(-a*sumD))
__global__ __launch_bounds__(256) void scan_pass1(
    const unsigned short* __restrict__ deltaT, const unsigned short* __restrict__ xn,
    float2* __restrict__ SP,
    const float* __restrict__ alog_f, const float* __restrict__ alog_b,
    const float* __restrict__ bp_f, const float* __restrict__ bp_b,
    int l, int NC, int CL) {
  const unsigned gid = blockIdx.x * 256u + threadIdx.x;
  const unsigned seq = gid & (NSEQ - 1u);
  const unsigned c = gid >> 17;
  const int n = seq & 15;
  const int d = (seq >> 4) & 255;
  const int b = (seq >> 12) & 15;
  const int dir = seq >> 16;
  const float* alog = dir ? alog_b : alog_f;
  const float* bp = dir ? bp_b : bp_f;
  const int widx = (l << 12) + (d << 4) + n;
  const float aneg = -(softplus_full(alog[widx]) + 1e-4f);
  const float bpv = bp[widx];
  const unsigned seqrow = (unsigned)((dir << 4) | b);
  const unsigned t0 = c * (unsigned)CL;
  const unsigned dbase = (((seqrow << 8) + (unsigned)d) << 11) + t0;
  const unsigned xbase = ((seqrow << 11) + t0) * 256u + (unsigned)d;

  float s = 0.f, dsum = 0.f;
  for (int tt = 0; tt < CL; tt += 8) {
    short8 dv = *(const short8*)&deltaT[dbase + (unsigned)tt];
    float xts[8];
#pragma unroll
    for (int k = 0; k < 8; ++k)
      xts[k] = bf2f(xn[xbase + (unsigned)(tt + k) * 256u]);
#pragma unroll
    for (int k = 0; k < 8; ++k) {
      float dt = bf2f((unsigned short)dv[k]);
      float e = __expf(aneg * dt);
      s = fmaf(e, s, dt * xts[k] * bpv);
      dsum += dt;
    }
  }
  float2 sp;
  sp.x = s;
  sp.y = __expf(aneg * dsum);
  SP[seq * (unsigned)NC + c] = sp;
}

// pass2: rebuild incoming state via chunk prefix, rescan, emit y (sum over n)
__global__ __launch_bounds__(256) void scan_pass2(
    const unsigned short* __restrict__ deltaT, const unsigned short* __restrict__ xn,
    unsigned short* __restrict__ y, const float2* __restrict__ SP,
    const float* __restrict__ alog_f, const float* __restrict__ alog_b,
    const float* __restrict__ bp_f, const float* __restrict__ bp_b,
    int l, int NC, int CL) {
  const unsigned gid = blockIdx.x * 256u + threadIdx.x;
  const unsigned seq = gid & (NSEQ - 1u);
  const unsigned c = gid >> 17;
  const int n = seq & 15;
  const int d = (seq >> 4) & 255;
  const int b = (seq >> 12) & 15;
  const int dir = seq >> 16;
  const float* alog = dir ? alog_b : alog_f;
  const float* bp = dir ? bp_b : bp_f;
  const int widx = (l << 12) + (d << 4) + n;
  const float aneg = -(softplus_full(alog[widx]) + 1e-4f);
  const float bpv = bp[widx];
  const unsigned seqrow = (unsigned)((dir << 4) | b);
  const unsigned t0 = c * (unsigned)CL;
  const unsigned dbase = (((seqrow << 8) + (unsigned)d) << 11) + t0;
  const unsigned xbase = ((seqrow << 11) + t0) * 256u + (unsigned)d;
  const bool writer = ((threadIdx.x & 15) == 0);

  float s = 0.f;
  for (unsigned j = 0; j < c; ++j) {
    float2 sp = SP[seq * (unsigned)NC + j];
    s = sp.x + sp.y * s;
  }

  for (int tt = 0; tt < CL; tt += 8) {
    short8 dv = *(const short8*)&deltaT[dbase + (unsigned)tt];
    float xts[8];
#pragma unroll
    for (int k = 0; k < 8; ++k)
      xts[k] = bf2f(xn[xbase + (unsigned)(tt + k) * 256u]);
#pragma unroll
    for (int k = 0; k < 8; ++k) {
      float dt = bf2f((unsigned short)dv[k]);
      float e = __expf(aneg * dt);
      s = fmaf(e, s, dt * xts[k] * bpv);
      float ys = s;
      ROR_ADD(ys, 0x128);  // row_ror:8
      ROR_ADD(ys, 0x124);  // row_ror:4
      ROR_ADD(ys, 0x122);  // row_ror:2
      ROR_ADD(ys, 0x121);  // row_ror:1
      if (writer) y[xbase + (unsigned)(tt + k) * 256u] = f2bf(ys);
    }
  }
}

// ---------------- fp32 -> bf16 convert (final x for merge GEMM)
__global__ __launch_bounds__(256) void tobf_kernel(const float4* __restrict__ src,
                                                   ushort4* __restrict__ dst) {
  unsigned idx = blockIdx.x * 256u + threadIdx.x;   // < 4,194,304
  float4 v = src[idx];
  dst[idx] = make_ushort4(f2bf(v.x), f2bf(v.y), f2bf(v.z), f2bf(v.w));
}

// ---------------- merge GEMM: [32768][512] (fwd|flipped-bwd) @ mergeT -> merged fp32
__global__ __launch_bounds__(256) void gemm_merge_k(
    const unsigned short* __restrict__ Xbf, const unsigned short* __restrict__ MT,
    const float* __restrict__ mb, float* __restrict__ merged) {
  __shared__ __align__(16) unsigned short As[128 * 32];
  __shared__ __align__(16) unsigned short Bs[128 * 32];
  const int tid = threadIdx.x;
  const int lane = tid & 63, wave = tid >> 6;
  const int wm = wave >> 1, wn = wave & 1;
  const int lrow = lane & 15, lhi = lane >> 4;
  const int r0 = blockIdx.y << 7;
  const int c0 = blockIdx.x << 7;

  f32x4 acc[4][4] = {};

  for (int k0 = 0; k0 < 512; k0 += 32) {
    __syncthreads();
#pragma unroll
    for (int r = 0; r < 2; ++r) {
      int chunk = (r << 8) + tid;
      int row = chunk >> 2, qq = chunk & 3;
      int gr = r0 + row;
      int b = gr >> 11, t = gr & 2047;
      unsigned srow, kk;
      if (k0 < 256) { srow = (unsigned)(b * 2048 + t); kk = (unsigned)k0; }
      else { srow = (unsigned)((16 + b) * 2048 + (2047 - t)); kk = (unsigned)(k0 - 256); }
      *(int4*)&As[chunk << 3] = *(const int4*)&Xbf[(srow << 8) + kk + (unsigned)(qq << 3)];
      *(int4*)&Bs[chunk << 3] =
          *(const int4*)&MT[(unsigned)(c0 + row) * 512u + (unsigned)(k0 + (qq << 3))];
    }
    __syncthreads();
    short8 af[4], bfr[4];
#pragma unroll
    for (int m = 0; m < 4; ++m)
      af[m] = *(const short8*)&As[((wm << 6) + (m << 4) + lrow) * 32 + (lhi << 3)];
#pragma unroll
    for (int n = 0; n < 4; ++n)
      bfr[n] = *(const short8*)&Bs[((wn << 6) + (n << 4) + lrow) * 32 + (lhi << 3)];
#pragma unroll
    for (int m = 0; m < 4; ++m)
#pragma unroll
      for (int n = 0; n < 4; ++n)
        acc[m][n] = __builtin_amdgcn_mfma_f32_16x16x32_bf16(af[m], bfr[n], acc[m][n], 0, 0, 0);
  }

#pragma unroll
  for (int m = 0; m < 4; ++m) {
#pragma unroll
    for (int n = 0; n < 4; ++n) {
      const int col = c0 + (wn << 6) + (n << 4) + lrow;
      const float bv = mb[col];
#pragma unroll
      for (int j = 0; j < 4; ++j) {
        const unsigned grow = (unsigned)(r0 + (wm << 6) + (m << 4) + (lhi << 2) + j);
        merged[grow * 256u + (unsigned)col] = acc[m][n][j] + bv;
      }
    }
  }
}

// ---------------- linear upsample x2 (align_corners=False)
__global__ __launch_bounds__(256) void up_kernel(const float4* __restrict__ m4,
                                                 float4* __restrict__ out4) {
  unsigned idx = blockIdx.x * 256u + threadIdx.x;   // < 4,194,304
  unsigned d4 = idx & 63u;
  unsigned t = (idx >> 6) & 4095u;
  unsigned b = idx >> 18;
  unsigned j = t >> 1;
  unsigned lo, hi; float wlo, whi;
  if (t & 1u) { lo = j; hi = (j < 2047u) ? j + 1u : 2047u; wlo = 0.75f; whi = 0.25f; }
  else { lo = j ? j - 1u : 0u; hi = j; wlo = 0.25f; whi = 0.75f; }
  float4 a = m4[((b << 11) + lo) * 64u + d4];
  float4 c = m4[((b << 11) + hi) * 64u + d4];
  float4 o;
  o.x = wlo * a.x + whi * c.x; o.y = wlo * a.y + whi * c.y;
  o.z = wlo * a.z + whi * c.z; o.w = wlo * a.w + whi * c.w;
  out4[((b << 12) + t) * 64u + d4] = o;
}

// ============================================================
extern "C" void kernel_launch(void* const* d_in, const int* in_sizes, int n_in,
                              void* d_out, int out_size, void* d_ws, size_t ws_size,
                              hipStream_t stream) {
  const float* x    = (const float*)d_in[0];
  const float* fnw  = (const float*)d_in[1];
  const float* fnb  = (const float*)d_in[2];
  const float* fdw  = (const float*)d_in[3];
  const float* fdb  = (const float*)d_in[4];
  const float* falog = (const float*)d_in[5];
  const float* fbp  = (const float*)d_in[6];
  const float* fow  = (const float*)d_in[7];
  const float* fob  = (const float*)d_in[8];
  const float* bnw  = (const float*)d_in[9];
  const float* bnb  = (const float*)d_in[10];
  const float* bdw  = (const float*)d_in[11];
  const float* bdb  = (const float*)d_in[12];
  const float* balog = (const float*)d_in[13];
  const float* bbp  = (const float*)d_in[14];
  const float* bow  = (const float*)d_in[15];
  const float* bob  = (const float*)d_in[16];
  const float* mw   = (const float*)d_in[17];
  const float* mb   = (const float*)d_in[18];

  char* ws = (char*)d_ws;
  const size_t SZ = 33554432;            // 16.78M bf16
  unsigned short* xn_bf    = (unsigned short*)(ws);
  unsigned short* deltaT   = (unsigned short*)(ws + SZ);
  unsigned short* y_bf     = (unsigned short*)(ws + 2 * SZ);
  unsigned short* dwT      = (unsigned short*)(ws + 3 * SZ);
  unsigned short* owT      = dwT + 524288;
  unsigned short* mergeT   = owT + 524288;
  float* merged            = (float*)(ws + SZ);    // overlay deltaT (dead by merge time)
  float* xw                = (float*)d_out;        // [2][16][2048][256] fp32 residual stream

  // chunk-state (S,P) pool after the weights; adaptive chunk count vs ws_size
  const size_t fixed = 3 * SZ + (524288 + 524288 + 131072) * sizeof(unsigned short);
  float2* SP = (float2*)(ws + fixed);
  size_t avail = ws_size > fixed ? ws_size - fixed : 0;
  int NC = 1;
  if (avail >= (size_t)NSEQ * 8 * sizeof(float2)) NC = 8;
  else if (avail >= (size_t)NSEQ * 4 * sizeof(float2)) NC = 4;
  else if (avail >= (size_t)NSEQ * 2 * sizeof(float2)) NC = 2;
  const int CL = TS / NC;

  wconv_kernel<<<4608, 256, 0, stream>>>(fdw, bdw, fow, bow, mw, dwT, owT, mergeT);
  ds_kernel<<<16384, 256, 0, stream>>>((const float4*)x, (float4*)xw);

  for (int l = 0; l < 4; ++l) {
    ln_kernel<<<16384, 256, 0, stream>>>(xw, xn_bf, fnw, fnb, bnw, bnb, l);
    gemm_layer_k<0><<<dim3(2, 512), 256, 0, stream>>>(xn_bf, dwT, fdb, bdb, l, deltaT, nullptr);
    if (NC > 1)
      scan_pass1<<<(NSEQ / 256) * (NC - 1), 256, 0, stream>>>(
          deltaT, xn_bf, SP, falog, balog, fbp, bbp, l, NC, CL);
    scan_pass2<<<(NSEQ / 256) * NC, 256, 0, stream>>>(
        deltaT, xn_bf, y_bf, SP, falog, balog, fbp, bbp, l, NC, CL);
    gemm_layer_k<1><<<dim3(2, 512), 256, 0, stream>>>(y_bf, owT, fob, bob, l, nullptr, xw);
  }

  tobf_kernel<<<16384, 256, 0, stream>>>((const float4*)xw, (ushort4*)xn_bf);
  gemm_merge_k<<<dim3(2, 256), 256, 0, stream>>>(xn_bf, mergeT, mb, merged);
  up_kernel<<<16384, 256, 0, stream>>>((const float4*)merged, (float4*)d_out);
}

// Round 3
// 1091.858 us; speedup vs baseline: 3.0299x; 1.3341x over previous
//
#include <hip/hip_runtime.h>

// ============================================================
// ScaleEncoder: pool2 -> [LN -> SSM-scan -> resid]x4 (fwd & bwd) -> merge -> upsample
// B=16 T=4096 D=256 N=16 L=4 SCALE=2, Ts=2048
// xw (fp32 residual stream, [2][16][2048][256]) lives in d_out (exactly 67.1MB).
// ws: xn_bf | deltaT(/merged f32 overlay) | y_bf | dwT | owT | mergeT | SP
// Scan: thread-per-(dir,b,d), 16 N-states in registers, bp folded out of the
// recurrence (s' = e*s' + dt*xt; y = sum_n bp_n * s'_n). Chunked 2-pass
// linear recurrence, NC chunks (adaptive by ws_size).
// ============================================================

typedef __attribute__((ext_vector_type(8))) short short8;
typedef __attribute__((ext_vector_type(4))) float f32x4;

#define TS 2048
#define NSEQ_D 8192u   // 2*16*256 per-(dir,b,d) recurrences (16 n each)

#if __has_builtin(__builtin_amdgcn_exp2f)
#define EXP2F(x) __builtin_amdgcn_exp2f(x)
#else
#define EXP2F(x) exp2f(x)
#endif
#if __has_builtin(__builtin_amdgcn_logf)
#define LOG2F(x) __builtin_amdgcn_logf(x)
#else
#define LOG2F(x) log2f(x)
#endif
#define LOG2E 1.44269504088896f
#define LN2 0.69314718055995f

__device__ __forceinline__ unsigned short f2bf(float f) {
  unsigned u = __float_as_uint(f);
  u = u + 0x7FFFu + ((u >> 16) & 1u);
  return (unsigned short)(u >> 16);
}
__device__ __forceinline__ float bf2f(unsigned short h) {
  return __uint_as_float(((unsigned)h) << 16);
}
// fast softplus: max(x,0) + ln2*log2(1 + 2^(-|x|*log2e))
__device__ __forceinline__ float softplus_fast(float x) {
  float e = EXP2F(-fabsf(x) * LOG2E);
  return fmaxf(x, 0.f) + LN2 * LOG2F(1.f + e);
}

// ---------------- downsample: x[16][4096][256] -> xw[2][16][2048][256]
__global__ __launch_bounds__(256) void ds_kernel(const float4* __restrict__ x4,
                                                 float4* __restrict__ xw4) {
  unsigned idx = blockIdx.x * 256u + threadIdx.x;   // < 4,194,304
  unsigned d4 = idx & 63u;
  unsigned j = (idx >> 6) & 2047u;
  unsigned b = (idx >> 17) & 15u;
  unsigned dir = idx >> 21;
  unsigned jj = dir ? (2047u - j) : j;
  unsigned srow = (b << 12) + (jj << 1);
  float4 v0 = x4[srow * 64u + d4];
  float4 v1 = x4[(srow + 1u) * 64u + d4];
  float4 o;
  o.x = 0.5f * (v0.x + v1.x); o.y = 0.5f * (v0.y + v1.y);
  o.z = 0.5f * (v0.z + v1.z); o.w = 0.5f * (v0.w + v1.w);
  xw4[(((dir << 4) + b) * 2048u + j) * 64u + d4] = o;
}

// ---------------- weight transpose+bf16
__global__ __launch_bounds__(256) void wconv_kernel(
    const float* __restrict__ fdw, const float* __restrict__ bdw,
    const float* __restrict__ fow, const float* __restrict__ bow,
    const float* __restrict__ mw,
    unsigned short* __restrict__ dwT, unsigned short* __restrict__ owT,
    unsigned short* __restrict__ mT) {
  unsigned idx = blockIdx.x * 256u + threadIdx.x;   // < 1,179,648
  if (idx < 524288u) {
    unsigned dir = idx >> 18, l = (idx >> 16) & 3u, n = (idx >> 8) & 255u, k = idx & 255u;
    const float* s = dir ? bdw : fdw;
    dwT[idx] = f2bf(s[((l << 8) + k) * 256u + n]);
  } else if (idx < 1048576u) {
    unsigned r = idx - 524288u;
    unsigned dir = r >> 18, l = (r >> 16) & 3u, n = (r >> 8) & 255u, k = r & 255u;
    const float* s = dir ? bow : fow;
    owT[r] = f2bf(s[((l << 8) + k) * 256u + n]);
  } else {
    unsigned r = idx - 1048576u;                    // < 131072
    unsigned n = r >> 9, k = r & 511u;
    mT[r] = f2bf(mw[(k << 8) + n]);
  }
}

// ---------------- LayerNorm: xw fp32 -> xn bf16 (one wave per 256-row)
__global__ __launch_bounds__(256) void ln_kernel(
    const float* __restrict__ xw, unsigned short* __restrict__ xn,
    const float* __restrict__ fnw, const float* __restrict__ fnb,
    const float* __restrict__ bnw, const float* __restrict__ bnb, int l) {
  unsigned row = (blockIdx.x << 2) + (threadIdx.x >> 6);  // < 65536
  unsigned lane = threadIdx.x & 63u;
  unsigned dir = row >> 15;
  const float* g = (dir ? bnw : fnw) + (l << 8);
  const float* bb = (dir ? bnb : fnb) + (l << 8);
  float4 v = ((const float4*)xw)[(row << 6) + lane];
  float s = v.x + v.y + v.z + v.w;
  float q = v.x * v.x + v.y * v.y + v.z * v.z + v.w * v.w;
  for (int o = 32; o > 0; o >>= 1) { s += __shfl_xor(s, o); q += __shfl_xor(q, o); }
  float m = s * (1.f / 256.f);
  float var = q * (1.f / 256.f) - m * m;
  float r = rsqrtf(var + 1e-5f);
  unsigned dd = lane << 2;
  ushort4 o4 = make_ushort4(
      f2bf((v.x - m) * r * g[dd + 0] + bb[dd + 0]),
      f2bf((v.y - m) * r * g[dd + 1] + bb[dd + 1]),
      f2bf((v.z - m) * r * g[dd + 2] + bb[dd + 2]),
      f2bf((v.w - m) * r * g[dd + 3] + bb[dd + 3]));
  ((ushort4*)xn)[(row << 6) + lane] = o4;
}

// ---------------- layer GEMM: C[65536][256] = A @ W_dir + bias_dir
// MODE 0: deltaT[dir,b,d,t] = softplus(C) bf16 (transposed, ushort4-packed along t).
// MODE 1: xw += C (residual, fp32).
template <int MODE>
__global__ __launch_bounds__(256) void gemm_layer_k(
    const unsigned short* __restrict__ Abf, const unsigned short* __restrict__ WT,
    const float* __restrict__ bias_f, const float* __restrict__ bias_b, int l,
    unsigned short* __restrict__ delta_out, float* __restrict__ xw) {
  __shared__ __align__(16) unsigned short As[128 * 32];
  __shared__ __align__(16) unsigned short Bs[128 * 32];
  const int tid = threadIdx.x;
  const int lane = tid & 63, wave = tid >> 6;
  const int wm = wave >> 1, wn = wave & 1;
  const int lrow = lane & 15, lhi = lane >> 4;
  const int r0 = blockIdx.y << 7;
  const int c0 = blockIdx.x << 7;
  const int dir = r0 >> 15;
  const unsigned short* W = WT + (((dir << 2) + l) << 16);
  const float* bias = (dir ? bias_b : bias_f) + (l << 8);

  f32x4 acc[4][4] = {};

  for (int k0 = 0; k0 < 256; k0 += 32) {
    __syncthreads();
#pragma unroll
    for (int r = 0; r < 2; ++r) {
      int chunk = (r << 8) + tid;
      int row = chunk >> 2, qq = chunk & 3;
      *(int4*)&As[chunk << 3] =
          *(const int4*)&Abf[(unsigned)(r0 + row) * 256u + (unsigned)(k0 + (qq << 3))];
      *(int4*)&Bs[chunk << 3] =
          *(const int4*)&W[(unsigned)(c0 + row) * 256u + (unsigned)(k0 + (qq << 3))];
    }
    __syncthreads();
    short8 af[4], bfr[4];
#pragma unroll
    for (int m = 0; m < 4; ++m)
      af[m] = *(const short8*)&As[((wm << 6) + (m << 4) + lrow) * 32 + (lhi << 3)];
#pragma unroll
    for (int n = 0; n < 4; ++n)
      bfr[n] = *(const short8*)&Bs[((wn << 6) + (n << 4) + lrow) * 32 + (lhi << 3)];
#pragma unroll
    for (int m = 0; m < 4; ++m)
#pragma unroll
      for (int n = 0; n < 4; ++n)
        acc[m][n] = __builtin_amdgcn_mfma_f32_16x16x32_bf16(af[m], bfr[n], acc[m][n], 0, 0, 0);
  }

  const int seqrow = r0 >> 11;           // dir*16 + b  (constant per block)
  const int tloc = r0 & 2047;            // t base of this block
#pragma unroll
  for (int m = 0; m < 4; ++m) {
#pragma unroll
    for (int n = 0; n < 4; ++n) {
      const int col = c0 + (wn << 6) + (n << 4) + lrow;
      const float bv = bias[col];
      if (MODE == 0) {
        ushort4 pk;
#pragma unroll
        for (int j = 0; j < 4; ++j) {
          float v = acc[m][n][j] + bv;
          ((unsigned short*)&pk)[j] = f2bf(softplus_fast(v));
        }
        const unsigned tb = (unsigned)(tloc + (wm << 6) + (m << 4) + (lhi << 2));
        *(ushort4*)&delta_out[(((unsigned)((seqrow << 8) + col)) << 11) + tb] = pk;
      } else {
#pragma unroll
        for (int j = 0; j < 4; ++j) {
          const unsigned grow = (unsigned)(r0 + (wm << 6) + (m << 4) + (lhi << 2) + j);
          xw[grow * 256u + (unsigned)col] += acc[m][n][j] + bv;
        }
      }
    }
  }
}

// ---------------- chunked SSM scan, thread-per-(dir,b,d) ----------------
// SP layout: per (seq, chunk): float4 x8 = S[0..15] | P[0..15]

// pass1: local scan of chunk c (c in [0, NC-1)), store (S_n, P_n=exp(-a_n*sumD))
__global__ __launch_bounds__(256) void scan_pass1(
    const unsigned short* __restrict__ deltaT, const unsigned short* __restrict__ xn,
    float4* __restrict__ SP,
    const float* __restrict__ alog_f, const float* __restrict__ alog_b,
    int l, int NC, int CL) {
  const unsigned gid = blockIdx.x * 256u + threadIdx.x;
  const unsigned seq = gid & (NSEQ_D - 1u);          // dir*4096 + b*256 + d
  const unsigned c = gid >> 13;
  const int d = seq & 255;
  const unsigned seqrow = seq >> 8;                  // dir*16 + b
  const int dir = seq >> 12;
  const float* alog = (dir ? alog_b : alog_f) + (((l << 8) + d) << 4);

  float c2[16];
#pragma unroll
  for (int q = 0; q < 4; ++q) {
    float4 av = ((const float4*)alog)[q];
    c2[q * 4 + 0] = -(softplus_fast(av.x) + 1e-4f) * LOG2E;
    c2[q * 4 + 1] = -(softplus_fast(av.y) + 1e-4f) * LOG2E;
    c2[q * 4 + 2] = -(softplus_fast(av.z) + 1e-4f) * LOG2E;
    c2[q * 4 + 3] = -(softplus_fast(av.w) + 1e-4f) * LOG2E;
  }

  const unsigned t0 = c * (unsigned)CL;
  const unsigned dbase = (seq << 11) + t0;
  const unsigned xbase = (seqrow << 19) + (t0 << 8) + (unsigned)d;

  float s[16];
#pragma unroll
  for (int n = 0; n < 16; ++n) s[n] = 0.f;
  float dsum = 0.f;

  for (int tt = 0; tt < CL; tt += 8) {
    short8 dv = *(const short8*)&deltaT[dbase + (unsigned)tt];
    float xt[8];
#pragma unroll
    for (int k = 0; k < 8; ++k)
      xt[k] = bf2f(xn[xbase + (unsigned)((tt + k) << 8)]);
#pragma unroll
    for (int k = 0; k < 8; ++k) {
      float dt = bf2f((unsigned short)dv[k]);
      float u = dt * xt[k];
      dsum += dt;
#pragma unroll
      for (int n = 0; n < 16; ++n)
        s[n] = fmaf(EXP2F(c2[n] * dt), s[n], u);
    }
  }

  float4* o = &SP[(seq * (unsigned)NC + c) << 3];
#pragma unroll
  for (int q = 0; q < 4; ++q) {
    float4 v; v.x = s[q * 4]; v.y = s[q * 4 + 1]; v.z = s[q * 4 + 2]; v.w = s[q * 4 + 3];
    o[q] = v;
  }
#pragma unroll
  for (int q = 0; q < 4; ++q) {
    float4 v;
    v.x = EXP2F(c2[q * 4 + 0] * dsum); v.y = EXP2F(c2[q * 4 + 1] * dsum);
    v.z = EXP2F(c2[q * 4 + 2] * dsum); v.w = EXP2F(c2[q * 4 + 3] * dsum);
    o[4 + q] = v;
  }
}

// pass2: rebuild incoming state from chunk prefix, rescan, emit y = sum_n bp_n*s_n
__global__ __launch_bounds__(256) void scan_pass2(
    const unsigned short* __restrict__ deltaT, const unsigned short* __restrict__ xn,
    unsigned short* __restrict__ y, const float4* __restrict__ SP,
    const float* __restrict__ alog_f, const float* __restrict__ alog_b,
    const float* __restrict__ bp_f, const float* __restrict__ bp_b,
    int l, int NC, int CL) {
  const unsigned gid = blockIdx.x * 256u + threadIdx.x;
  const unsigned seq = gid & (NSEQ_D - 1u);
  const unsigned c = gid >> 13;
  const int d = seq & 255;
  const unsigned seqrow = seq >> 8;
  const int dir = seq >> 12;
  const float* alog = (dir ? alog_b : alog_f) + (((l << 8) + d) << 4);
  const float* bpp = (dir ? bp_b : bp_f) + (((l << 8) + d) << 4);

  float c2[16], bp[16];
#pragma unroll
  for (int q = 0; q < 4; ++q) {
    float4 av = ((const float4*)alog)[q];
    c2[q * 4 + 0] = -(softplus_fast(av.x) + 1e-4f) * LOG2E;
    c2[q * 4 + 1] = -(softplus_fast(av.y) + 1e-4f) * LOG2E;
    c2[q * 4 + 2] = -(softplus_fast(av.z) + 1e-4f) * LOG2E;
    c2[q * 4 + 3] = -(softplus_fast(av.w) + 1e-4f) * LOG2E;
    float4 bv = ((const float4*)bpp)[q];
    bp[q * 4 + 0] = bv.x; bp[q * 4 + 1] = bv.y; bp[q * 4 + 2] = bv.z; bp[q * 4 + 3] = bv.w;
  }

  float s[16];
#pragma unroll
  for (int n = 0; n < 16; ++n) s[n] = 0.f;

  // chunk-prefix: s = S_j + P_j * s over j = 0..c-1
  const float4* spb = &SP[(seq * (unsigned)NC) << 3];
  for (unsigned j = 0; j < c; ++j) {
#pragma unroll
    for (int q = 0; q < 4; ++q) {
      float4 S = spb[(j << 3) + q];
      float4 P = spb[(j << 3) + 4 + q];
      s[q * 4 + 0] = fmaf(P.x, s[q * 4 + 0], S.x);
      s[q * 4 + 1] = fmaf(P.y, s[q * 4 + 1], S.y);
      s[q * 4 + 2] = fmaf(P.z, s[q * 4 + 2], S.z);
      s[q * 4 + 3] = fmaf(P.w, s[q * 4 + 3], S.w);
    }
  }

  const unsigned t0 = c * (unsigned)CL;
  const unsigned dbase = (seq << 11) + t0;
  const unsigned xbase = (seqrow << 19) + (t0 << 8) + (unsigned)d;

  for (int tt = 0; tt < CL; tt += 8) {
    short8 dv = *(const short8*)&deltaT[dbase + (unsigned)tt];
    float xt[8];
#pragma unroll
    for (int k = 0; k < 8; ++k)
      xt[k] = bf2f(xn[xbase + (unsigned)((tt + k) << 8)]);
#pragma unroll
    for (int k = 0; k < 8; ++k) {
      float dt = bf2f((unsigned short)dv[k]);
      float u = dt * xt[k];
#pragma unroll
      for (int n = 0; n < 16; ++n)
        s[n] = fmaf(EXP2F(c2[n] * dt), s[n], u);
      float ya = bp[0] * s[0], yb = bp[1] * s[1], yc = bp[2] * s[2], yd = bp[3] * s[3];
      ya = fmaf(bp[4], s[4], ya);   yb = fmaf(bp[5], s[5], yb);
      yc = fmaf(bp[6], s[6], yc);   yd = fmaf(bp[7], s[7], yd);
      ya = fmaf(bp[8], s[8], ya);   yb = fmaf(bp[9], s[9], yb);
      yc = fmaf(bp[10], s[10], yc); yd = fmaf(bp[11], s[11], yd);
      ya = fmaf(bp[12], s[12], ya); yb = fmaf(bp[13], s[13], yb);
      yc = fmaf(bp[14], s[14], yc); yd = fmaf(bp[15], s[15], yd);
      float ys = (ya + yb) + (yc + yd);
      y[xbase + (unsigned)((tt + k) << 8)] = f2bf(ys);
    }
  }
}

// ---------------- fp32 -> bf16 convert (final x for merge GEMM)
__global__ __launch_bounds__(256) void tobf_kernel(const float4* __restrict__ src,
                                                   ushort4* __restrict__ dst) {
  unsigned idx = blockIdx.x * 256u + threadIdx.x;   // < 4,194,304
  float4 v = src[idx];
  dst[idx] = make_ushort4(f2bf(v.x), f2bf(v.y), f2bf(v.z), f2bf(v.w));
}

// ---------------- merge GEMM: [32768][512] (fwd|flipped-bwd) @ mergeT -> merged fp32
__global__ __launch_bounds__(256) void gemm_merge_k(
    const unsigned short* __restrict__ Xbf, const unsigned short* __restrict__ MT,
    const float* __restrict__ mb, float* __restrict__ merged) {
  __shared__ __align__(16) unsigned short As[128 * 32];
  __shared__ __align__(16) unsigned short Bs[128 * 32];
  const int tid = threadIdx.x;
  const int lane = tid & 63, wave = tid >> 6;
  const int wm = wave >> 1, wn = wave & 1;
  const int lrow = lane & 15, lhi = lane >> 4;
  const int r0 = blockIdx.y << 7;
  const int c0 = blockIdx.x << 7;

  f32x4 acc[4][4] = {};

  for (int k0 = 0; k0 < 512; k0 += 32) {
    __syncthreads();
#pragma unroll
    for (int r = 0; r < 2; ++r) {
      int chunk = (r << 8) + tid;
      int row = chunk >> 2, qq = chunk & 3;
      int gr = r0 + row;
      int b = gr >> 11, t = gr & 2047;
      unsigned srow, kk;
      if (k0 < 256) { srow = (unsigned)(b * 2048 + t); kk = (unsigned)k0; }
      else { srow = (unsigned)((16 + b) * 2048 + (2047 - t)); kk = (unsigned)(k0 - 256); }
      *(int4*)&As[chunk << 3] = *(const int4*)&Xbf[(srow << 8) + kk + (unsigned)(qq << 3)];
      *(int4*)&Bs[chunk << 3] =
          *(const int4*)&MT[(unsigned)(c0 + row) * 512u + (unsigned)(k0 + (qq << 3))];
    }
    __syncthreads();
    short8 af[4], bfr[4];
#pragma unroll
    for (int m = 0; m < 4; ++m)
      af[m] = *(const short8*)&As[((wm << 6) + (m << 4) + lrow) * 32 + (lhi << 3)];
#pragma unroll
    for (int n = 0; n < 4; ++n)
      bfr[n] = *(const short8*)&Bs[((wn << 6) + (n << 4) + lrow) * 32 + (lhi << 3)];
#pragma unroll
    for (int m = 0; m < 4; ++m)
#pragma unroll
      for (int n = 0; n < 4; ++n)
        acc[m][n] = __builtin_amdgcn_mfma_f32_16x16x32_bf16(af[m], bfr[n], acc[m][n], 0, 0, 0);
  }

#pragma unroll
  for (int m = 0; m < 4; ++m) {
#pragma unroll
    for (int n = 0; n < 4; ++n) {
      const int col = c0 + (wn << 6) + (n << 4) + lrow;
      const float bv = mb[col];
#pragma unroll
      for (int j = 0; j < 4; ++j) {
        const unsigned grow = (unsigned)(r0 + (wm << 6) + (m << 4) + (lhi << 2) + j);
        merged[grow * 256u + (unsigned)col] = acc[m][n][j] + bv;
      }
    }
  }
}

// ---------------- linear upsample x2 (align_corners=False)
__global__ __launch_bounds__(256) void up_kernel(const float4* __restrict__ m4,
                                                 float4* __restrict__ out4) {
  unsigned idx = blockIdx.x * 256u + threadIdx.x;   // < 4,194,304
  unsigned d4 = idx & 63u;
  unsigned t = (idx >> 6) & 4095u;
  unsigned b = idx >> 18;
  unsigned j = t >> 1;
  unsigned lo, hi; float wlo, whi;
  if (t & 1u) { lo = j; hi = (j < 2047u) ? j + 1u : 2047u; wlo = 0.75f; whi = 0.25f; }
  else { lo = j ? j - 1u : 0u; hi = j; wlo = 0.25f; whi = 0.75f; }
  float4 a = m4[((b << 11) + lo) * 64u + d4];
  float4 c = m4[((b << 11) + hi) * 64u + d4];
  float4 o;
  o.x = wlo * a.x + whi * c.x; o.y = wlo * a.y + whi * c.y;
  o.z = wlo * a.z + whi * c.z; o.w = wlo * a.w + whi * c.w;
  out4[((b << 12) + t) * 64u + d4] = o;
}

// ============================================================
extern "C" void kernel_launch(void* const* d_in, const int* in_sizes, int n_in,
                              void* d_out, int out_size, void* d_ws, size_t ws_size,
                              hipStream_t stream) {
  const float* x    = (const float*)d_in[0];
  const float* fnw  = (const float*)d_in[1];
  const float* fnb  = (const float*)d_in[2];
  const float* fdw  = (const float*)d_in[3];
  const float* fdb  = (const float*)d_in[4];
  const float* falog = (const float*)d_in[5];
  const float* fbp  = (const float*)d_in[6];
  const float* fow  = (const float*)d_in[7];
  const float* fob  = (const float*)d_in[8];
  const float* bnw  = (const float*)d_in[9];
  const float* bnb  = (const float*)d_in[10];
  const float* bdw  = (const float*)d_in[11];
  const float* bdb  = (const float*)d_in[12];
  const float* balog = (const float*)d_in[13];
  const float* bbp  = (const float*)d_in[14];
  const float* bow  = (const float*)d_in[15];
  const float* bob  = (const float*)d_in[16];
  const float* mw   = (const float*)d_in[17];
  const float* mb   = (const float*)d_in[18];

  char* ws = (char*)d_ws;
  const size_t SZ = 33554432;            // 16.78M bf16
  unsigned short* xn_bf    = (unsigned short*)(ws);
  unsigned short* deltaT   = (unsigned short*)(ws + SZ);
  unsigned short* y_bf     = (unsigned short*)(ws + 2 * SZ);
  unsigned short* dwT      = (unsigned short*)(ws + 3 * SZ);
  unsigned short* owT      = dwT + 524288;
  unsigned short* mergeT   = owT + 524288;
  float* merged            = (float*)(ws + SZ);    // overlay deltaT (dead by merge time)
  float* xw                = (float*)d_out;        // [2][16][2048][256] fp32 residual stream

  // chunk-state pool: per (seq=8192, chunk): 32 floats (16 S + 16 P) = 128B
  const size_t fixed = 3 * SZ + (524288 + 524288 + 131072) * sizeof(unsigned short);
  float4* SP = (float4*)(ws + fixed);
  size_t avail = ws_size > fixed ? ws_size - fixed : 0;
  int NC = 1;
  if (avail >= (size_t)NSEQ_D * 32 * 128) NC = 32;
  else if (avail >= (size_t)NSEQ_D * 16 * 128) NC = 16;
  else if (avail >= (size_t)NSEQ_D * 8 * 128) NC = 8;
  else if (avail >= (size_t)NSEQ_D * 4 * 128) NC = 4;
  else if (avail >= (size_t)NSEQ_D * 2 * 128) NC = 2;
  const int CL = TS / NC;

  wconv_kernel<<<4608, 256, 0, stream>>>(fdw, bdw, fow, bow, mw, dwT, owT, mergeT);
  ds_kernel<<<16384, 256, 0, stream>>>((const float4*)x, (float4*)xw);

  for (int l = 0; l < 4; ++l) {
    ln_kernel<<<16384, 256, 0, stream>>>(xw, xn_bf, fnw, fnb, bnw, bnb, l);
    gemm_layer_k<0><<<dim3(2, 512), 256, 0, stream>>>(xn_bf, dwT, fdb, bdb, l, deltaT, nullptr);
    if (NC > 1)
      scan_pass1<<<32 * (NC - 1), 256, 0, stream>>>(
          deltaT, xn_bf, SP, falog, balog, l, NC, CL);
    scan_pass2<<<32 * NC, 256, 0, stream>>>(
        deltaT, xn_bf, y_bf, SP, falog, balog, fbp, bbp, l, NC, CL);
    gemm_layer_k<1><<<dim3(2, 512), 256, 0, stream>>>(y_bf, owT, fob, bob, l, nullptr, xw);
  }

  tobf_kernel<<<16384, 256, 0, stream>>>((const float4*)xw, (ushort4*)xn_bf);
  gemm_merge_k<<<dim3(2, 256), 256, 0, stream>>>(xn_bf, mergeT, mb, merged);
  up_kernel<<<16384, 256, 0, stream>>>((const float4*)merged, (float4*)d_out);
}